// Round 1
// baseline (4759.818 us; speedup 1.0000x reference)
//
#include <hip/hip_runtime.h>
#include <hip/hip_bf16.h>

#define N_NODES 100000

// ---------------------------------------------------------------- degree ----
__global__ __launch_bounds__(256) void init_deg_kernel(float* deg, int n) {
    int i = blockIdx.x * 256 + threadIdx.x;
    if (i < n) deg[i] = 1.0f;  // self-loop contributes 1
}

__global__ __launch_bounds__(256) void deg_accum_kernel(float* deg, const int* __restrict__ dst, int E) {
    int stride = gridDim.x * 256;
    for (int e = blockIdx.x * 256 + threadIdx.x; e < E; e += stride)
        atomicAdd(&deg[dst[e]], 1.0f);
}

__global__ __launch_bounds__(256) void rsqrt_kernel(float* deg, int n) {
    int i = blockIdx.x * 256 + threadIdx.x;
    if (i < n) deg[i] = rsqrtf(deg[i]);  // deg >= 1 always
}

// ---------------------------------------------------------------- GEMM ------
// h[r][0:128] = x[r][0:128] @ W[128][128].  One wave per row; W in LDS;
// x row held as float2 per lane, broadcast via shuffle.
__global__ __launch_bounds__(256) void gemm128_kernel(const float* __restrict__ x,
                                                      const float* __restrict__ W,
                                                      float* __restrict__ h, int nrows) {
    __shared__ float Wl[128 * 128];
    int tid = threadIdx.x;
#pragma unroll
    for (int i = 0; i < 16; ++i) {
        int idx = (i * 256 + tid) * 4;
        *(float4*)&Wl[idx] = *(const float4*)&W[idx];
    }
    __syncthreads();
    int wid = tid >> 6, lane = tid & 63;
    int gw = blockIdx.x * 4 + wid;
    int nw = gridDim.x * 4;
    for (int r = gw; r < nrows; r += nw) {
        float2 xv = *(const float2*)&x[r * 128 + 2 * lane];
        float acc0 = 0.f, acc1 = 0.f;
#pragma unroll
        for (int k = 0; k < 128; k += 2) {
            float xa = __shfl(xv.x, k >> 1);
            float xb = __shfl(xv.y, k >> 1);
            float2 wa = *(const float2*)&Wl[k * 128 + 2 * lane];
            float2 wb = *(const float2*)&Wl[(k + 1) * 128 + 2 * lane];
            acc0 += xa * wa.x; acc1 += xa * wa.y;
            acc0 += xb * wb.x; acc1 += xb * wb.y;
        }
        *(float2*)&h[r * 128 + 2 * lane] = make_float2(acc0, acc1);
    }
}

// h[r][0:64] = x[r][0:128] @ W[128][64].  One wave per row, lane = out col.
__global__ __launch_bounds__(256) void gemm64_kernel(const float* __restrict__ x,
                                                     const float* __restrict__ W,
                                                     float* __restrict__ h, int nrows) {
    __shared__ float Wl[128 * 64];
    int tid = threadIdx.x;
#pragma unroll
    for (int i = 0; i < 8; ++i) {
        int idx = (i * 256 + tid) * 4;
        *(float4*)&Wl[idx] = *(const float4*)&W[idx];
    }
    __syncthreads();
    int wid = tid >> 6, lane = tid & 63;
    int gw = blockIdx.x * 4 + wid;
    int nw = gridDim.x * 4;
    for (int r = gw; r < nrows; r += nw) {
        float2 xv = *(const float2*)&x[r * 128 + 2 * lane];
        float acc = 0.f;
#pragma unroll
        for (int k = 0; k < 128; k += 2) {
            float xa = __shfl(xv.x, k >> 1);
            float xb = __shfl(xv.y, k >> 1);
            acc += xa * Wl[k * 64 + lane];
            acc += xb * Wl[(k + 1) * 64 + lane];
        }
        h[r * 64 + lane] = acc;
    }
}

// ------------------------------------------------------------ aggregation ---
// g[n][c] = h[n][c] * dinv[n]^2   (self-loop term; also zero-initializes g)
template <int D>
__global__ __launch_bounds__(256) void agg_init_kernel(const float* __restrict__ h,
                                                       const float* __restrict__ dinv,
                                                       float* __restrict__ g, int n) {
    const int CH = D / 4;  // float4 chunks per row
    int i = blockIdx.x * 256 + threadIdx.x;  // chunk index
    if (i >= n * CH) return;
    int node = i / CH;
    float s = dinv[node];
    s = s * s;
    float4 v = ((const float4*)h)[i];
    v.x *= s; v.y *= s; v.z *= s; v.w *= s;
    ((float4*)g)[i] = v;
}

// g[dst] += h[src] * dinv[src]*dinv[dst], one thread per (edge, 4-col chunk)
template <int D>
__global__ __launch_bounds__(256) void agg_edges_kernel(const float* __restrict__ h,
                                                        float* __restrict__ g,
                                                        const int* __restrict__ src,
                                                        const int* __restrict__ dst,
                                                        const float* __restrict__ dinv,
                                                        int E) {
    const int CH = D / 4;
    int total = E * CH;
    int stride = gridDim.x * 256;
    for (int t = blockIdx.x * 256 + threadIdx.x; t < total; t += stride) {
        int e = t / CH;
        int c = (t % CH) * 4;
        int s = src[e], d = dst[e];
        float norm = dinv[s] * dinv[d];
        const float4 v = *(const float4*)&h[s * D + c];
        float* gp = &g[d * D + c];
        atomicAdd(gp + 0, v.x * norm);
        atomicAdd(gp + 1, v.y * norm);
        atomicAdd(gp + 2, v.z * norm);
        atomicAdd(gp + 3, v.w * norm);
    }
}

// ------------------------------------------------------------- epilogues ----
__global__ __launch_bounds__(256) void bias_relu_kernel(float* __restrict__ g,
                                                        const float* __restrict__ b, int n) {
    int i = blockIdx.x * 256 + threadIdx.x;  // float4 chunk over [n*128]
    if (i >= n * 32) return;
    int c = (i & 31) * 4;
    float4 v = ((float4*)g)[i];
    v.x = fmaxf(v.x + b[c + 0], 0.f);
    v.y = fmaxf(v.y + b[c + 1], 0.f);
    v.z = fmaxf(v.z + b[c + 2], 0.f);
    v.w = fmaxf(v.w + b[c + 3], 0.f);
    ((float4*)g)[i] = v;
}

__global__ __launch_bounds__(256) void logsoftmax_kernel(const float* __restrict__ g,
                                                         const float* __restrict__ b,
                                                         float* __restrict__ out, int n) {
    int wid = threadIdx.x >> 6, lane = threadIdx.x & 63;
    int r = blockIdx.x * 4 + wid;
    if (r >= n) return;
    float v = g[r * 64 + lane] + b[lane];
    float m = v;
#pragma unroll
    for (int off = 32; off; off >>= 1) m = fmaxf(m, __shfl_xor(m, off));
    float ex = __expf(v - m);
    float s = ex;
#pragma unroll
    for (int off = 32; off; off >>= 1) s += __shfl_xor(s, off);
    out[r * 64 + lane] = v - m - __logf(s);
}

// ---------------------------------------------------------------- launch ----
extern "C" void kernel_launch(void* const* d_in, const int* in_sizes, int n_in,
                              void* d_out, int out_size, void* d_ws, size_t ws_size,
                              hipStream_t stream) {
    const float* x  = (const float*)d_in[0];
    const int*   ei = (const int*)d_in[1];
    const float* W1 = (const float*)d_in[2];
    const float* b1 = (const float*)d_in[3];
    const float* W2 = (const float*)d_in[4];
    const float* b2 = (const float*)d_in[5];
    float* out = (float*)d_out;

    const int N = N_NODES;
    const int E = in_sizes[1] / 2;
    const int* src = ei;
    const int* dst = ei + E;

    char* ws = (char*)d_ws;
    float* dinv = (float*)ws;                                  // 100000 f32
    float* bufA = (float*)(ws + (4ll << 20));                  // 51.2 MB
    float* bufB = (float*)(ws + (4ll << 20) + (52ll << 20));   // 51.2 MB

    // degree + dinv
    init_deg_kernel<<<(N + 255) / 256, 256, 0, stream>>>(dinv, N);
    deg_accum_kernel<<<1024, 256, 0, stream>>>(dinv, dst, E);
    rsqrt_kernel<<<(N + 255) / 256, 256, 0, stream>>>(dinv, N);

    // layer 1: h1 = x @ W1  -> bufA
    gemm128_kernel<<<2048, 256, 0, stream>>>(x, W1, bufA, N);
    // g1 = scatter(h1) -> bufB
    agg_init_kernel<128><<<(N * 32 + 255) / 256, 256, 0, stream>>>(bufA, dinv, bufB, N);
    agg_edges_kernel<128><<<8192, 256, 0, stream>>>(bufA, bufB, src, dst, dinv, E);
    // relu(g1 + b1) in place
    bias_relu_kernel<<<(N * 32 + 255) / 256, 256, 0, stream>>>(bufB, b1, N);

    // layer 2: h2 = g1 @ W2 -> bufA (h1 dead)
    gemm64_kernel<<<2048, 256, 0, stream>>>(bufB, W2, bufA, N);
    // g2 = scatter(h2) -> bufB (g1 dead after gemm64)
    agg_init_kernel<64><<<(N * 16 + 255) / 256, 256, 0, stream>>>(bufA, dinv, bufB, N);
    agg_edges_kernel<64><<<8192, 256, 0, stream>>>(bufA, bufB, src, dst, dinv, E);

    // out = log_softmax(g2 + b2)
    logsoftmax_kernel<<<(N + 3) / 4, 256, 0, stream>>>(bufB, b2, out, N);
}

// Round 2
// 1106.553 us; speedup vs baseline: 4.3015x; 4.3015x over previous
//
#include <hip/hip_runtime.h>
#include <hip/hip_bf16.h>

#define N_NODES 100000

// ---------------------------------------------------------- CSR build -------
__global__ __launch_bounds__(256) void zero_count_kernel(int* count, int n) {
    int i = blockIdx.x * 256 + threadIdx.x;
    if (i < n) count[i] = 0;
}

__global__ __launch_bounds__(256) void hist_kernel(int* count, const int* __restrict__ dst, int E) {
    int e = blockIdx.x * 256 + threadIdx.x;
    if (e < E) atomicAdd(&count[dst[e]], 1);
}

// per-block exclusive scan; block sums to aux
__global__ __launch_bounds__(256) void scan1_kernel(const int* __restrict__ count,
                                                    int* __restrict__ offs,
                                                    int* __restrict__ aux, int n) {
    __shared__ int sm[256];
    int tid = threadIdx.x;
    int i = blockIdx.x * 256 + tid;
    int v = (i < n) ? count[i] : 0;
    sm[tid] = v;
    __syncthreads();
#pragma unroll
    for (int off = 1; off < 256; off <<= 1) {
        int t = (tid >= off) ? sm[tid - off] : 0;
        __syncthreads();
        sm[tid] += t;
        __syncthreads();
    }
    if (i < n) offs[i] = sm[tid] - v;  // exclusive within block
    if (tid == 255) aux[blockIdx.x] = sm[255];
}

// exclusive scan of block sums (nb <= 512), single block of 512 threads
__global__ __launch_bounds__(512) void scan2_kernel(int* __restrict__ aux, int nb) {
    __shared__ int sm[512];
    int tid = threadIdx.x;
    int v = (tid < nb) ? aux[tid] : 0;
    sm[tid] = v;
    __syncthreads();
#pragma unroll
    for (int off = 1; off < 512; off <<= 1) {
        int t = (tid >= off) ? sm[tid - off] : 0;
        __syncthreads();
        sm[tid] += t;
        __syncthreads();
    }
    if (tid < nb) aux[tid] = sm[tid] - v;  // exclusive
}

// finalize offs, init cursor, compute dinv from count (+1 self-loop)
__global__ __launch_bounds__(256) void scan3_kernel(int* __restrict__ offs,
                                                    const int* __restrict__ aux,
                                                    int* __restrict__ cursor,
                                                    const int* __restrict__ count,
                                                    float* __restrict__ dinv,
                                                    int n, int E) {
    int i = blockIdx.x * 256 + threadIdx.x;
    if (i >= n) return;
    int o = offs[i] + aux[blockIdx.x];
    offs[i] = o;
    cursor[i] = o;
    dinv[i] = rsqrtf((float)count[i] + 1.0f);
    if (i == 0) offs[n] = E;
}

__global__ __launch_bounds__(256) void fill_kernel(const int* __restrict__ src,
                                                   const int* __restrict__ dst,
                                                   int* __restrict__ cursor,
                                                   int* __restrict__ adj, int E) {
    int e = blockIdx.x * 256 + threadIdx.x;
    if (e >= E) return;
    int p = atomicAdd(&cursor[dst[e]], 1);
    adj[p] = src[e];
}

// ---------------------------------------------------------------- GEMM ------
// h[r][0:128] = x[r][0:128] @ W[128][128].  One wave per row; W in LDS.
__global__ __launch_bounds__(256) void gemm128_kernel(const float* __restrict__ x,
                                                      const float* __restrict__ W,
                                                      float* __restrict__ h, int nrows) {
    __shared__ float Wl[128 * 128];
    int tid = threadIdx.x;
#pragma unroll
    for (int i = 0; i < 16; ++i) {
        int idx = (i * 256 + tid) * 4;
        *(float4*)&Wl[idx] = *(const float4*)&W[idx];
    }
    __syncthreads();
    int wid = tid >> 6, lane = tid & 63;
    int gw = blockIdx.x * 4 + wid;
    int nw = gridDim.x * 4;
    for (int r = gw; r < nrows; r += nw) {
        float2 xv = *(const float2*)&x[r * 128 + 2 * lane];
        float acc0 = 0.f, acc1 = 0.f;
#pragma unroll
        for (int k = 0; k < 128; k += 2) {
            float xa = __shfl(xv.x, k >> 1);
            float xb = __shfl(xv.y, k >> 1);
            float2 wa = *(const float2*)&Wl[k * 128 + 2 * lane];
            float2 wb = *(const float2*)&Wl[(k + 1) * 128 + 2 * lane];
            acc0 += xa * wa.x; acc1 += xa * wa.y;
            acc0 += xb * wb.x; acc1 += xb * wb.y;
        }
        *(float2*)&h[r * 128 + 2 * lane] = make_float2(acc0, acc1);
    }
}

// h[r][0:64] = x[r][0:128] @ W[128][64].  One wave per row, lane = out col.
__global__ __launch_bounds__(256) void gemm64_kernel(const float* __restrict__ x,
                                                     const float* __restrict__ W,
                                                     float* __restrict__ h, int nrows) {
    __shared__ float Wl[128 * 64];
    int tid = threadIdx.x;
#pragma unroll
    for (int i = 0; i < 8; ++i) {
        int idx = (i * 256 + tid) * 4;
        *(float4*)&Wl[idx] = *(const float4*)&W[idx];
    }
    __syncthreads();
    int wid = tid >> 6, lane = tid & 63;
    int gw = blockIdx.x * 4 + wid;
    int nw = gridDim.x * 4;
    for (int r = gw; r < nrows; r += nw) {
        float2 xv = *(const float2*)&x[r * 128 + 2 * lane];
        float acc = 0.f;
#pragma unroll
        for (int k = 0; k < 128; k += 2) {
            float xa = __shfl(xv.x, k >> 1);
            float xb = __shfl(xv.y, k >> 1);
            acc += xa * Wl[k * 64 + lane];
            acc += xb * Wl[(k + 1) * 64 + lane];
        }
        h[r * 64 + lane] = acc;
    }
}

// ----------------------------------------------------------- gather aggs ----
// out[r] = relu( dinv[r]*(dinv[r]*h[r] + sum_j dinv[s_j]*h[s_j]) + b )
__global__ __launch_bounds__(256) void gather128_kernel(const float* __restrict__ h,
                                                        const int* __restrict__ offs,
                                                        const int* __restrict__ adj,
                                                        const float* __restrict__ dinv,
                                                        const float* __restrict__ b,
                                                        float* __restrict__ g, int n) {
    int wid = threadIdx.x >> 6, lane = threadIdx.x & 63;
    int r = blockIdx.x * 4 + wid;
    if (r >= n) return;
    float dr = dinv[r];
    float2 hv = *(const float2*)&h[r * 128 + 2 * lane];
    float accx = hv.x * dr, accy = hv.y * dr;
    int e0 = offs[r], e1 = offs[r + 1];
    int s_next = (e0 < e1) ? adj[e0] : 0;
    for (int j = e0; j < e1; ++j) {
        int s = s_next;
        s_next = (j + 1 < e1) ? adj[j + 1] : 0;
        float ds = dinv[s];
        float2 v = *(const float2*)&h[s * 128 + 2 * lane];
        accx += ds * v.x;
        accy += ds * v.y;
    }
    accx = fmaxf(accx * dr + b[2 * lane], 0.f);
    accy = fmaxf(accy * dr + b[2 * lane + 1], 0.f);
    *(float2*)&g[r * 128 + 2 * lane] = make_float2(accx, accy);
}

// fused gather + bias + log_softmax over 64 cols (lane = col)
__global__ __launch_bounds__(256) void gather64_lsm_kernel(const float* __restrict__ h,
                                                           const int* __restrict__ offs,
                                                           const int* __restrict__ adj,
                                                           const float* __restrict__ dinv,
                                                           const float* __restrict__ b,
                                                           float* __restrict__ out, int n) {
    int wid = threadIdx.x >> 6, lane = threadIdx.x & 63;
    int r = blockIdx.x * 4 + wid;
    if (r >= n) return;
    float dr = dinv[r];
    float acc = h[r * 64 + lane] * dr;
    int e0 = offs[r], e1 = offs[r + 1];
    int s_next = (e0 < e1) ? adj[e0] : 0;
    for (int j = e0; j < e1; ++j) {
        int s = s_next;
        s_next = (j + 1 < e1) ? adj[j + 1] : 0;
        acc += dinv[s] * h[s * 64 + lane];
    }
    float v = acc * dr + b[lane];
    float m = v;
#pragma unroll
    for (int off = 32; off; off >>= 1) m = fmaxf(m, __shfl_xor(m, off));
    float ex = __expf(v - m);
    float sum = ex;
#pragma unroll
    for (int off = 32; off; off >>= 1) sum += __shfl_xor(sum, off);
    out[r * 64 + lane] = v - m - __logf(sum);
}

// ---------------------------------------------------------------- launch ----
extern "C" void kernel_launch(void* const* d_in, const int* in_sizes, int n_in,
                              void* d_out, int out_size, void* d_ws, size_t ws_size,
                              hipStream_t stream) {
    const float* x  = (const float*)d_in[0];
    const int*   ei = (const int*)d_in[1];
    const float* W1 = (const float*)d_in[2];
    const float* b1 = (const float*)d_in[3];
    const float* W2 = (const float*)d_in[4];
    const float* b2 = (const float*)d_in[5];
    float* out = (float*)d_out;

    const int N = N_NODES;
    const int E = in_sizes[1] / 2;
    const int* src = ei;
    const int* dst = ei + E;

    char* ws = (char*)d_ws;
    float* dinv  = (float*)(ws + (0ll << 20));   // 400 KB
    int* count   = (int*)  (ws + (1ll << 20));   // 400 KB (reused as cursor)
    int* offs    = (int*)  (ws + (2ll << 20));   // 400 KB (+1)
    int* aux     = (int*)  (ws + (3ll << 20));   // 2 KB
    int* adj     = (int*)  (ws + (4ll << 20));   // 6.4 MB
    float* bufA  = (float*)(ws + (12ll << 20));  // 51.2 MB
    float* bufB  = (float*)(ws + (64ll << 20));  // 51.2 MB

    const int NB = (N + 255) / 256;  // 391 scan blocks

    // ---- CSR build (by dst) + dinv ----
    zero_count_kernel<<<NB, 256, 0, stream>>>(count, N);
    hist_kernel<<<(E + 255) / 256, 256, 0, stream>>>(count, dst, E);
    scan1_kernel<<<NB, 256, 0, stream>>>(count, offs, aux, N);
    scan2_kernel<<<1, 512, 0, stream>>>(aux, NB);
    scan3_kernel<<<NB, 256, 0, stream>>>(offs, aux, count /*cursor*/, count, dinv, N, E);
    fill_kernel<<<(E + 255) / 256, 256, 0, stream>>>(src, dst, count /*cursor*/, adj, E);

    // ---- layer 1 ----
    gemm128_kernel<<<2048, 256, 0, stream>>>(x, W1, bufA, N);
    gather128_kernel<<<(N + 3) / 4, 256, 0, stream>>>(bufA, offs, adj, dinv, b1, bufB, N);

    // ---- layer 2 ----
    gemm64_kernel<<<2048, 256, 0, stream>>>(bufB, W2, bufA, N);
    gather64_lsm_kernel<<<(N + 3) / 4, 256, 0, stream>>>(bufA, offs, adj, dinv, b2, out, N);
}

// Round 3
// 602.765 us; speedup vs baseline: 7.8966x; 1.8358x over previous
//
#include <hip/hip_runtime.h>
#include <hip/hip_bf16.h>
#include <stdint.h>

#define N_NODES 100000

typedef short short8 __attribute__((ext_vector_type(8)));
typedef float floatx4 __attribute__((ext_vector_type(4)));

__device__ __forceinline__ unsigned short f2bf(float x) {
    uint32_t u = __float_as_uint(x);
    return (unsigned short)((u + 0x7fff + ((u >> 16) & 1)) >> 16);  // RNE
}
__device__ __forceinline__ float bf2f(unsigned int h) {
    return __uint_as_float(h << 16);
}

// ---------------------------------------------------------- CSR build -------
__global__ __launch_bounds__(256) void zero_count_kernel(int* count, int n) {
    int i = blockIdx.x * 256 + threadIdx.x;
    if (i < n) count[i] = 0;
}

__global__ __launch_bounds__(256) void hist_kernel(int* count, const int* __restrict__ dst, int E) {
    int e = blockIdx.x * 256 + threadIdx.x;
    if (e < E) atomicAdd(&count[dst[e]], 1);
}

__global__ __launch_bounds__(256) void scan1_kernel(const int* __restrict__ count,
                                                    int* __restrict__ offs,
                                                    int* __restrict__ aux, int n) {
    __shared__ int sm[256];
    int tid = threadIdx.x;
    int i = blockIdx.x * 256 + tid;
    int v = (i < n) ? count[i] : 0;
    sm[tid] = v;
    __syncthreads();
#pragma unroll
    for (int off = 1; off < 256; off <<= 1) {
        int t = (tid >= off) ? sm[tid - off] : 0;
        __syncthreads();
        sm[tid] += t;
        __syncthreads();
    }
    if (i < n) offs[i] = sm[tid] - v;
    if (tid == 255) aux[blockIdx.x] = sm[255];
}

__global__ __launch_bounds__(512) void scan2_kernel(int* __restrict__ aux, int nb) {
    __shared__ int sm[512];
    int tid = threadIdx.x;
    int v = (tid < nb) ? aux[tid] : 0;
    sm[tid] = v;
    __syncthreads();
#pragma unroll
    for (int off = 1; off < 512; off <<= 1) {
        int t = (tid >= off) ? sm[tid - off] : 0;
        __syncthreads();
        sm[tid] += t;
        __syncthreads();
    }
    if (tid < nb) aux[tid] = sm[tid] - v;
}

__global__ __launch_bounds__(256) void scan3_kernel(int* __restrict__ offs,
                                                    const int* __restrict__ aux,
                                                    int* __restrict__ cursor,
                                                    const int* __restrict__ count,
                                                    float* __restrict__ dinv,
                                                    int n, int E) {
    int i = blockIdx.x * 256 + threadIdx.x;
    if (i >= n) return;
    int o = offs[i] + aux[blockIdx.x];
    offs[i] = o;
    cursor[i] = o;
    dinv[i] = rsqrtf((float)count[i] + 1.0f);
    if (i == 0) offs[n] = E;
}

__global__ __launch_bounds__(256) void fill_kernel(const int* __restrict__ src,
                                                   const int* __restrict__ dst,
                                                   int* __restrict__ cursor,
                                                   int* __restrict__ adj, int E) {
    int e = blockIdx.x * 256 + threadIdx.x;
    if (e >= E) return;
    int p = atomicAdd(&cursor[dst[e]], 1);
    adj[p] = src[e];
}

// ------------------------------------------------------- fp32 -> bf16 hi/lo -
__global__ __launch_bounds__(256) void convx_kernel(const float* __restrict__ x,
                                                    unsigned short* __restrict__ xh,
                                                    unsigned short* __restrict__ xl, int total4) {
    int i = blockIdx.x * 256 + threadIdx.x;
    if (i >= total4) return;
    float4 v = ((const float4*)x)[i];
    ushort4 h, l;
    h.x = f2bf(v.x); l.x = f2bf(v.x - bf2f(h.x));
    h.y = f2bf(v.y); l.y = f2bf(v.y - bf2f(h.y));
    h.z = f2bf(v.z); l.z = f2bf(v.z - bf2f(h.z));
    h.w = f2bf(v.w); l.w = f2bf(v.w - bf2f(h.w));
    ((ushort4*)xh)[i] = h;
    ((ushort4*)xl)[i] = l;
}

// W [128 k][N n] fp32  ->  Wt hi/lo [N n][128 k] bf16 (transposed, linear)
__global__ __launch_bounds__(256) void convw_kernel(const float* __restrict__ W,
                                                    unsigned short* __restrict__ WtH,
                                                    unsigned short* __restrict__ WtL, int N) {
    int i = blockIdx.x * 256 + threadIdx.x;  // i = n*128 + k
    if (i >= N * 128) return;
    int n = i >> 7, k = i & 127;
    float v = W[k * N + n];
    unsigned short h = f2bf(v);
    WtH[i] = h;
    WtL[i] = f2bf(v - bf2f(h));
}

// ------------------------------------------------------------- MFMA GEMM ----
// C[r][:] = dinv[r] * (A[r][:] @ W)   with A = Ah+Al (bf16 split), W = Wt hi/lo.
// 3-product: Ah*Wh + Al*Wh + Ah*Wl.  Wave = 32 rows x N cols, block = 128 rows.
template <int N, bool SPLIT_OUT>
__global__ __launch_bounds__(256) void gemm_mfma_kernel(
    const unsigned short* __restrict__ Ah, const unsigned short* __restrict__ Al,
    const unsigned short* __restrict__ WtH, const unsigned short* __restrict__ WtL,
    const float* __restrict__ dinv,
    unsigned short* __restrict__ Ch, unsigned short* __restrict__ Cl,
    float* __restrict__ Cf, int nrows) {
    constexpr int NT = N / 16;
    __shared__ char Wl[2 * N * 256];  // hi then lo, 256 B per n-row, XOR-swizzled
    int tid = threadIdx.x;
    {
        const char* s0 = (const char*)WtH;
        const char* s1 = (const char*)WtL;
        const int chunks = N * 16;  // 16B chunks per buffer
        for (int i = tid; i < 2 * chunks; i += 256) {
            int buf = (i >= chunks) ? 1 : 0;
            int c = i - buf * chunks;
            int nn = c >> 4;
            float4 v = *(const float4*)((buf ? s1 : s0) + c * 16);
            int dstoff = (c * 16) ^ ((nn & 7) << 4);
            *(float4*)(Wl + buf * (N * 256) + dstoff) = v;
        }
    }
    __syncthreads();

    int wid = tid >> 6, lane = tid & 63;
    int rowbase = blockIdx.x * 128 + wid * 32;
    int lr = lane & 15, lg = lane >> 4;

    floatx4 acc[2][NT] = {};
    for (int ks = 0; ks < 4; ++ks) {
        short8 afh[2], afl[2];
#pragma unroll
        for (int rt = 0; rt < 2; ++rt) {
            int r = rowbase + rt * 16 + lr;
            if (r > nrows - 1) r = nrows - 1;
            size_t off = (size_t)r * 128 + ks * 32 + (lg << 3);
            afh[rt] = *(const short8*)(Ah + off);
            afl[rt] = *(const short8*)(Al + off);
        }
#pragma unroll
        for (int t = 0; t < NT; ++t) {
            int nn = t * 16 + lr;
            int off = (nn * 256 + ks * 64 + (lg << 4)) ^ ((nn & 7) << 4);
            short8 bh = *(const short8*)(Wl + off);
            short8 bl = *(const short8*)(Wl + N * 256 + off);
#pragma unroll
            for (int rt = 0; rt < 2; ++rt) {
                acc[rt][t] = __builtin_amdgcn_mfma_f32_16x16x32_bf16(afh[rt], bh, acc[rt][t], 0, 0, 0);
                acc[rt][t] = __builtin_amdgcn_mfma_f32_16x16x32_bf16(afl[rt], bh, acc[rt][t], 0, 0, 0);
                acc[rt][t] = __builtin_amdgcn_mfma_f32_16x16x32_bf16(afh[rt], bl, acc[rt][t], 0, 0, 0);
            }
        }
    }
#pragma unroll
    for (int rt = 0; rt < 2; ++rt) {
#pragma unroll
        for (int j = 0; j < 4; ++j) {
            int row = rowbase + rt * 16 + lg * 4 + j;
            if (row >= nrows) continue;
            float dv = dinv[row];
#pragma unroll
            for (int t = 0; t < NT; ++t) {
                int col = t * 16 + lr;
                float v = acc[rt][t][j] * dv;
                if (SPLIT_OUT) {
                    unsigned short h = f2bf(v);
                    Ch[(size_t)row * N + col] = h;
                    Cl[(size_t)row * N + col] = f2bf(v - bf2f(h));
                } else {
                    Cf[(size_t)row * N + col] = v;
                }
            }
        }
    }
}

// ----------------------------------------------------------- gather aggs ----
// g[r] = relu(dr * (hs[r] + sum_adj hs[s]) + b), hs pre-scaled by dinv; bf16 hi/lo IO
__global__ __launch_bounds__(256) void gather128_kernel(
    const unsigned short* __restrict__ hh, const unsigned short* __restrict__ hl,
    const int* __restrict__ offs, const int* __restrict__ adj,
    const float* __restrict__ dinv, const float* __restrict__ b,
    unsigned short* __restrict__ gh, unsigned short* __restrict__ gl, int n) {
    int wid = threadIdx.x >> 6, lane = threadIdx.x & 63;
    int r = blockIdx.x * 4 + wid;
    if (r >= n) return;
    float dr = dinv[r];
    uint32_t vh = *(const uint32_t*)(hh + (size_t)r * 128 + 2 * lane);
    uint32_t vl = *(const uint32_t*)(hl + (size_t)r * 128 + 2 * lane);
    float accx = bf2f(vh & 0xffffu) + bf2f(vl & 0xffffu);
    float accy = bf2f(vh >> 16) + bf2f(vl >> 16);
    int e0 = offs[r], e1 = offs[r + 1];
    int s_next = (e0 < e1) ? adj[e0] : 0;
    for (int j = e0; j < e1; ++j) {
        int s = s_next;
        s_next = (j + 1 < e1) ? adj[j + 1] : 0;
        uint32_t uh = *(const uint32_t*)(hh + (size_t)s * 128 + 2 * lane);
        uint32_t ul = *(const uint32_t*)(hl + (size_t)s * 128 + 2 * lane);
        accx += bf2f(uh & 0xffffu) + bf2f(ul & 0xffffu);
        accy += bf2f(uh >> 16) + bf2f(ul >> 16);
    }
    accx = fmaxf(fmaf(accx, dr, b[2 * lane]), 0.f);
    accy = fmaxf(fmaf(accy, dr, b[2 * lane + 1]), 0.f);
    unsigned short hx = f2bf(accx), hy = f2bf(accy);
    *(uint32_t*)(gh + (size_t)r * 128 + 2 * lane) = (uint32_t)hx | ((uint32_t)hy << 16);
    unsigned short lx = f2bf(accx - bf2f(hx)), ly = f2bf(accy - bf2f(hy));
    *(uint32_t*)(gl + (size_t)r * 128 + 2 * lane) = (uint32_t)lx | ((uint32_t)ly << 16);
}

// fused gather + bias + log_softmax over 64 cols (h2 fp32, pre-scaled by dinv)
__global__ __launch_bounds__(256) void gather64_lsm_kernel(const float* __restrict__ h,
                                                           const int* __restrict__ offs,
                                                           const int* __restrict__ adj,
                                                           const float* __restrict__ dinv,
                                                           const float* __restrict__ b,
                                                           float* __restrict__ out, int n) {
    int wid = threadIdx.x >> 6, lane = threadIdx.x & 63;
    int r = blockIdx.x * 4 + wid;
    if (r >= n) return;
    float dr = dinv[r];
    float acc = h[(size_t)r * 64 + lane];
    int e0 = offs[r], e1 = offs[r + 1];
    int s_next = (e0 < e1) ? adj[e0] : 0;
    for (int j = e0; j < e1; ++j) {
        int s = s_next;
        s_next = (j + 1 < e1) ? adj[j + 1] : 0;
        acc += h[(size_t)s * 64 + lane];
    }
    float v = fmaf(acc, dr, b[lane]);
    float m = v;
#pragma unroll
    for (int off = 32; off; off >>= 1) m = fmaxf(m, __shfl_xor(m, off));
    float ex = __expf(v - m);
    float sum = ex;
#pragma unroll
    for (int off = 32; off; off >>= 1) sum += __shfl_xor(sum, off);
    out[(size_t)r * 64 + lane] = v - m - __logf(sum);
}

// ---------------------------------------------------------------- launch ----
extern "C" void kernel_launch(void* const* d_in, const int* in_sizes, int n_in,
                              void* d_out, int out_size, void* d_ws, size_t ws_size,
                              hipStream_t stream) {
    const float* x  = (const float*)d_in[0];
    const int*   ei = (const int*)d_in[1];
    const float* W1 = (const float*)d_in[2];
    const float* b1 = (const float*)d_in[3];
    const float* W2 = (const float*)d_in[4];
    const float* b2 = (const float*)d_in[5];
    float* out = (float*)d_out;

    const int N = N_NODES;
    const int E = in_sizes[1] / 2;
    const int* src = ei;
    const int* dst = ei + E;

    char* ws = (char*)d_ws;
    float* dinv  = (float*)(ws + (0ll << 20));
    int* count   = (int*)  (ws + (1ll << 20));
    int* offs    = (int*)  (ws + (2ll << 20));
    int* aux     = (int*)  (ws + (3ll << 20));
    unsigned short* Wt1h = (unsigned short*)(ws + (3ll << 20) + 0x10000);
    unsigned short* Wt1l = (unsigned short*)(ws + (3ll << 20) + 0x18000);
    unsigned short* Wt2h = (unsigned short*)(ws + (3ll << 20) + 0x20000);
    unsigned short* Wt2l = (unsigned short*)(ws + (3ll << 20) + 0x24000);
    int* adj     = (int*)  (ws + (4ll << 20));                 // 6.4 MB
    unsigned short* xh  = (unsigned short*)(ws + (11ll << 20)); // 25.6 MB (later g1h)
    unsigned short* xl  = (unsigned short*)(ws + (37ll << 20)); // 25.6 MB (later g1l)
    unsigned short* h1h = (unsigned short*)(ws + (63ll << 20)); // 25.6 MB (later h2)
    unsigned short* h1l = (unsigned short*)(ws + (89ll << 20)); // 25.6 MB
    unsigned short* g1h = xh;
    unsigned short* g1l = xl;
    float* h2 = (float*)h1h;

    const int NB = (N + 255) / 256;  // 391

    // ---- CSR build (by dst) + dinv ----
    zero_count_kernel<<<NB, 256, 0, stream>>>(count, N);
    hist_kernel<<<(E + 255) / 256, 256, 0, stream>>>(count, dst, E);
    scan1_kernel<<<NB, 256, 0, stream>>>(count, offs, aux, N);
    scan2_kernel<<<1, 512, 0, stream>>>(aux, NB);
    scan3_kernel<<<NB, 256, 0, stream>>>(offs, aux, count /*cursor*/, count, dinv, N, E);
    fill_kernel<<<(E + 255) / 256, 256, 0, stream>>>(src, dst, count /*cursor*/, adj, E);

    // ---- bf16 hi/lo conversions ----
    convx_kernel<<<(N * 32 + 255) / 256, 256, 0, stream>>>(x, xh, xl, N * 32);
    convw_kernel<<<(128 * 128 + 255) / 256, 256, 0, stream>>>(W1, Wt1h, Wt1l, 128);
    convw_kernel<<<(64 * 128 + 255) / 256, 256, 0, stream>>>(W2, Wt2h, Wt2l, 64);

    const int GB = (N + 127) / 128;  // 782 gemm blocks

    // ---- layer 1 ----
    gemm_mfma_kernel<128, true><<<GB, 256, 0, stream>>>(xh, xl, Wt1h, Wt1l, dinv,
                                                        h1h, h1l, nullptr, N);
    gather128_kernel<<<(N + 3) / 4, 256, 0, stream>>>(h1h, h1l, offs, adj, dinv, b1, g1h, g1l, N);

    // ---- layer 2 ----
    gemm_mfma_kernel<64, false><<<GB, 256, 0, stream>>>(g1h, g1l, Wt2h, Wt2l, dinv,
                                                        nullptr, nullptr, h2, N);
    gather64_lsm_kernel<<<(N + 3) / 4, 256, 0, stream>>>(h2, offs, adj, dinv, b2, out, N);
}

// Round 4
// 411.245 us; speedup vs baseline: 11.5742x; 1.4657x over previous
//
#include <hip/hip_runtime.h>
#include <hip/hip_bf16.h>
#include <stdint.h>

#define N_NODES 100000

typedef short short8 __attribute__((ext_vector_type(8)));
typedef float floatx4 __attribute__((ext_vector_type(4)));

__device__ __forceinline__ unsigned short f2bf(float x) {
    uint32_t u = __float_as_uint(x);
    return (unsigned short)((u + 0x7fff + ((u >> 16) & 1)) >> 16);  // RNE
}
__device__ __forceinline__ float bf2f(unsigned int h) {
    return __uint_as_float(h << 16);
}

// ---------------------------------------------------------- CSR build -------
__global__ __launch_bounds__(256) void zero_count_kernel(int* count, int n) {
    int i = blockIdx.x * 256 + threadIdx.x;
    if (i < n) count[i] = 0;
}

__global__ __launch_bounds__(256) void hist_kernel(int* count, const int* __restrict__ dst, int E) {
    int e = blockIdx.x * 256 + threadIdx.x;
    if (e < E) atomicAdd(&count[dst[e]], 1);
}

__global__ __launch_bounds__(256) void scan1_kernel(const int* __restrict__ count,
                                                    int* __restrict__ offs,
                                                    int* __restrict__ aux, int n) {
    __shared__ int sm[256];
    int tid = threadIdx.x;
    int i = blockIdx.x * 256 + tid;
    int v = (i < n) ? count[i] : 0;
    sm[tid] = v;
    __syncthreads();
#pragma unroll
    for (int off = 1; off < 256; off <<= 1) {
        int t = (tid >= off) ? sm[tid - off] : 0;
        __syncthreads();
        sm[tid] += t;
        __syncthreads();
    }
    if (i < n) offs[i] = sm[tid] - v;
    if (tid == 255) aux[blockIdx.x] = sm[255];
}

__global__ __launch_bounds__(512) void scan2_kernel(int* __restrict__ aux, int nb) {
    __shared__ int sm[512];
    int tid = threadIdx.x;
    int v = (tid < nb) ? aux[tid] : 0;
    sm[tid] = v;
    __syncthreads();
#pragma unroll
    for (int off = 1; off < 512; off <<= 1) {
        int t = (tid >= off) ? sm[tid - off] : 0;
        __syncthreads();
        sm[tid] += t;
        __syncthreads();
    }
    if (tid < nb) aux[tid] = sm[tid] - v;
}

__global__ __launch_bounds__(256) void scan3_kernel(int* __restrict__ offs,
                                                    const int* __restrict__ aux,
                                                    int* __restrict__ cursor,
                                                    const int* __restrict__ count,
                                                    float* __restrict__ dinv,
                                                    int n, int E) {
    int i = blockIdx.x * 256 + threadIdx.x;
    if (i >= n) return;
    int o = offs[i] + aux[blockIdx.x];
    offs[i] = o;
    cursor[i] = o;
    dinv[i] = rsqrtf((float)count[i] + 1.0f);
    if (i == 0) offs[n] = E;
}

__global__ __launch_bounds__(256) void fill_kernel(const int* __restrict__ src,
                                                   const int* __restrict__ dst,
                                                   int* __restrict__ cursor,
                                                   int* __restrict__ adj, int E) {
    int e = blockIdx.x * 256 + threadIdx.x;
    if (e >= E) return;
    int p = atomicAdd(&cursor[dst[e]], 1);
    adj[p] = src[e];
}

// W [128 k][N n] fp32  ->  Wt hi/lo [N n][128 k] bf16 (transposed, linear)
__global__ __launch_bounds__(256) void convw_kernel(const float* __restrict__ W,
                                                    unsigned short* __restrict__ WtH,
                                                    unsigned short* __restrict__ WtL, int N) {
    int i = blockIdx.x * 256 + threadIdx.x;  // i = n*128 + k
    if (i >= N * 128) return;
    int n = i >> 7, k = i & 127;
    float v = W[k * N + n];
    unsigned short h = f2bf(v);
    WtH[i] = h;
    WtL[i] = f2bf(v - bf2f(h));
}

// ------------------------------------------------------------- MFMA GEMM ----
// C[r][:] = dinv[r] * (A[r][:] @ W), 3-product bf16 split (Ah*Wh+Al*Wh+Ah*Wl).
// SPLIT_IN:  A read as fp32 and split in-register (Af), else bf16 hi/lo (Ah,Al).
// SPLIT_OUT: C written as bf16 hi/lo (Ch,Cl), else fp32 (Cf).
__device__ __forceinline__ void split8(const float* p, short8& h, short8& l) {
    float4 a = *(const float4*)p;
    float4 b = *(const float4*)(p + 4);
    float v[8] = {a.x, a.y, a.z, a.w, b.x, b.y, b.z, b.w};
#pragma unroll
    for (int i = 0; i < 8; ++i) {
        unsigned short hh = f2bf(v[i]);
        h[i] = (short)hh;
        l[i] = (short)f2bf(v[i] - bf2f(hh));
    }
}

template <int N, bool SPLIT_IN, bool SPLIT_OUT>
__global__ __launch_bounds__(256) void gemm_mfma_kernel(
    const float* __restrict__ Af,
    const unsigned short* __restrict__ Ah, const unsigned short* __restrict__ Al,
    const unsigned short* __restrict__ WtH, const unsigned short* __restrict__ WtL,
    const float* __restrict__ dinv,
    unsigned short* __restrict__ Ch, unsigned short* __restrict__ Cl,
    float* __restrict__ Cf, int nrows) {
    constexpr int NT = N / 16;
    __shared__ char Wl[2 * N * 256];  // hi then lo, 256 B per n-row, XOR-swizzled
    int tid = threadIdx.x;
    {
        const char* s0 = (const char*)WtH;
        const char* s1 = (const char*)WtL;
        const int chunks = N * 16;  // 16B chunks per buffer
        for (int i = tid; i < 2 * chunks; i += 256) {
            int buf = (i >= chunks) ? 1 : 0;
            int c = i - buf * chunks;
            int nn = c >> 4;
            float4 v = *(const float4*)((buf ? s1 : s0) + c * 16);
            int dstoff = (c * 16) ^ ((nn & 7) << 4);
            *(float4*)(Wl + buf * (N * 256) + dstoff) = v;
        }
    }
    __syncthreads();

    int wid = tid >> 6, lane = tid & 63;
    int rowbase = blockIdx.x * 128 + wid * 32;
    int lr = lane & 15, lg = lane >> 4;

    floatx4 acc[2][NT] = {};
    for (int ks = 0; ks < 4; ++ks) {
        short8 afh[2], afl[2];
#pragma unroll
        for (int rt = 0; rt < 2; ++rt) {
            int r = rowbase + rt * 16 + lr;
            if (r > nrows - 1) r = nrows - 1;
            size_t off = (size_t)r * 128 + ks * 32 + (lg << 3);
            if (SPLIT_IN) {
                split8(Af + off, afh[rt], afl[rt]);
            } else {
                afh[rt] = *(const short8*)(Ah + off);
                afl[rt] = *(const short8*)(Al + off);
            }
        }
#pragma unroll
        for (int t = 0; t < NT; ++t) {
            int nn = t * 16 + lr;
            int off = (nn * 256 + ks * 64 + (lg << 4)) ^ ((nn & 7) << 4);
            short8 bh = *(const short8*)(Wl + off);
            short8 bl = *(const short8*)(Wl + N * 256 + off);
#pragma unroll
            for (int rt = 0; rt < 2; ++rt) {
                acc[rt][t] = __builtin_amdgcn_mfma_f32_16x16x32_bf16(afh[rt], bh, acc[rt][t], 0, 0, 0);
                acc[rt][t] = __builtin_amdgcn_mfma_f32_16x16x32_bf16(afl[rt], bh, acc[rt][t], 0, 0, 0);
                acc[rt][t] = __builtin_amdgcn_mfma_f32_16x16x32_bf16(afh[rt], bl, acc[rt][t], 0, 0, 0);
            }
        }
    }
#pragma unroll
    for (int rt = 0; rt < 2; ++rt) {
#pragma unroll
        for (int j = 0; j < 4; ++j) {
            int row = rowbase + rt * 16 + lg * 4 + j;
            if (row >= nrows) continue;
            float dv = dinv[row];
#pragma unroll
            for (int t = 0; t < NT; ++t) {
                int col = t * 16 + lr;
                float v = acc[rt][t][j] * dv;
                if (SPLIT_OUT) {
                    unsigned short h = f2bf(v);
                    Ch[(size_t)row * N + col] = h;
                    Cl[(size_t)row * N + col] = f2bf(v - bf2f(h));
                } else {
                    Cf[(size_t)row * N + col] = v;
                }
            }
        }
    }
}

// ----------------------------------------------------------- gather aggs ----
// g[r] = relu(dr * (self_hi+lo + sum_adj hi) + b); h pre-scaled by dinv[src].
// Neighbor reads are bf16-hi ONLY (halves random-gather bytes).
__global__ __launch_bounds__(256) void gather128_kernel(
    const unsigned short* __restrict__ hh, const unsigned short* __restrict__ hl,
    const int* __restrict__ offs, const int* __restrict__ adj,
    const float* __restrict__ dinv, const float* __restrict__ b,
    unsigned short* __restrict__ gh, unsigned short* __restrict__ gl, int n) {
    int wid = threadIdx.x >> 6, lane = threadIdx.x & 63;
    int r = blockIdx.x * 4 + wid;
    if (r >= n) return;
    float dr = dinv[r];
    uint32_t vh = *(const uint32_t*)(hh + (size_t)r * 128 + 2 * lane);
    uint32_t vl = *(const uint32_t*)(hl + (size_t)r * 128 + 2 * lane);
    float a0x = bf2f(vh & 0xffffu) + bf2f(vl & 0xffffu);
    float a0y = bf2f(vh >> 16) + bf2f(vl >> 16);
    float a1x = 0.f, a1y = 0.f, a2x = 0.f, a2y = 0.f, a3x = 0.f, a3y = 0.f;
    int e0 = offs[r], e1 = offs[r + 1];
    int j = e0;
    for (; j + 4 <= e1; j += 4) {
        int s0 = adj[j], s1 = adj[j + 1], s2 = adj[j + 2], s3 = adj[j + 3];
        uint32_t u0 = *(const uint32_t*)(hh + (size_t)s0 * 128 + 2 * lane);
        uint32_t u1 = *(const uint32_t*)(hh + (size_t)s1 * 128 + 2 * lane);
        uint32_t u2 = *(const uint32_t*)(hh + (size_t)s2 * 128 + 2 * lane);
        uint32_t u3 = *(const uint32_t*)(hh + (size_t)s3 * 128 + 2 * lane);
        a0x += bf2f(u0 & 0xffffu); a0y += bf2f(u0 >> 16);
        a1x += bf2f(u1 & 0xffffu); a1y += bf2f(u1 >> 16);
        a2x += bf2f(u2 & 0xffffu); a2y += bf2f(u2 >> 16);
        a3x += bf2f(u3 & 0xffffu); a3y += bf2f(u3 >> 16);
    }
    for (; j < e1; ++j) {
        int s = adj[j];
        uint32_t u = *(const uint32_t*)(hh + (size_t)s * 128 + 2 * lane);
        a0x += bf2f(u & 0xffffu); a0y += bf2f(u >> 16);
    }
    float accx = (a0x + a1x) + (a2x + a3x);
    float accy = (a0y + a1y) + (a2y + a3y);
    accx = fmaxf(fmaf(accx, dr, b[2 * lane]), 0.f);
    accy = fmaxf(fmaf(accy, dr, b[2 * lane + 1]), 0.f);
    unsigned short hx = f2bf(accx), hy = f2bf(accy);
    *(uint32_t*)(gh + (size_t)r * 128 + 2 * lane) = (uint32_t)hx | ((uint32_t)hy << 16);
    unsigned short lx = f2bf(accx - bf2f(hx)), ly = f2bf(accy - bf2f(hy));
    *(uint32_t*)(gl + (size_t)r * 128 + 2 * lane) = (uint32_t)lx | ((uint32_t)ly << 16);
}

// fused gather + bias + log_softmax over 64 cols (h2 fp32, pre-scaled by dinv)
__global__ __launch_bounds__(256) void gather64_lsm_kernel(const float* __restrict__ h,
                                                           const int* __restrict__ offs,
                                                           const int* __restrict__ adj,
                                                           const float* __restrict__ dinv,
                                                           const float* __restrict__ b,
                                                           float* __restrict__ out, int n) {
    int wid = threadIdx.x >> 6, lane = threadIdx.x & 63;
    int r = blockIdx.x * 4 + wid;
    if (r >= n) return;
    float dr = dinv[r];
    float a0 = h[(size_t)r * 64 + lane];
    float a1 = 0.f, a2 = 0.f, a3 = 0.f;
    int e0 = offs[r], e1 = offs[r + 1];
    int j = e0;
    for (; j + 4 <= e1; j += 4) {
        int s0 = adj[j], s1 = adj[j + 1], s2 = adj[j + 2], s3 = adj[j + 3];
        a0 += h[(size_t)s0 * 64 + lane];
        a1 += h[(size_t)s1 * 64 + lane];
        a2 += h[(size_t)s2 * 64 + lane];
        a3 += h[(size_t)s3 * 64 + lane];
    }
    for (; j < e1; ++j) a0 += h[(size_t)adj[j] * 64 + lane];
    float acc = (a0 + a1) + (a2 + a3);
    float v = fmaf(acc, dr, b[lane]);
    float m = v;
#pragma unroll
    for (int off = 32; off; off >>= 1) m = fmaxf(m, __shfl_xor(m, off));
    float ex = __expf(v - m);
    float sum = ex;
#pragma unroll
    for (int off = 32; off; off >>= 1) sum += __shfl_xor(sum, off);
    out[(size_t)r * 64 + lane] = v - m - __logf(sum);
}

// ---------------------------------------------------------------- launch ----
extern "C" void kernel_launch(void* const* d_in, const int* in_sizes, int n_in,
                              void* d_out, int out_size, void* d_ws, size_t ws_size,
                              hipStream_t stream) {
    const float* x  = (const float*)d_in[0];
    const int*   ei = (const int*)d_in[1];
    const float* W1 = (const float*)d_in[2];
    const float* b1 = (const float*)d_in[3];
    const float* W2 = (const float*)d_in[4];
    const float* b2 = (const float*)d_in[5];
    float* out = (float*)d_out;

    const int N = N_NODES;
    const int E = in_sizes[1] / 2;
    const int* src = ei;
    const int* dst = ei + E;

    char* ws = (char*)d_ws;
    float* dinv  = (float*)(ws + (0ll << 20));
    int* count   = (int*)  (ws + (1ll << 20));
    int* offs    = (int*)  (ws + (2ll << 20));
    int* aux     = (int*)  (ws + (3ll << 20));
    unsigned short* Wt1h = (unsigned short*)(ws + (3ll << 20) + 0x10000);
    unsigned short* Wt1l = (unsigned short*)(ws + (3ll << 20) + 0x18000);
    unsigned short* Wt2h = (unsigned short*)(ws + (3ll << 20) + 0x20000);
    unsigned short* Wt2l = (unsigned short*)(ws + (3ll << 20) + 0x24000);
    int* adj     = (int*)  (ws + (4ll << 20));                  // 6.4 MB
    unsigned short* g1h = (unsigned short*)(ws + (11ll << 20)); // 25.6 MB
    unsigned short* g1l = (unsigned short*)(ws + (37ll << 20)); // 25.6 MB
    unsigned short* h1h = (unsigned short*)(ws + (63ll << 20)); // 25.6 MB (later h2 fp32)
    unsigned short* h1l = (unsigned short*)(ws + (89ll << 20)); // 25.6 MB
    float* h2 = (float*)h1h;

    const int NB = (N + 255) / 256;  // 391

    // ---- CSR build (by dst) + dinv ----
    zero_count_kernel<<<NB, 256, 0, stream>>>(count, N);
    hist_kernel<<<(E + 255) / 256, 256, 0, stream>>>(count, dst, E);
    scan1_kernel<<<NB, 256, 0, stream>>>(count, offs, aux, N);
    scan2_kernel<<<1, 512, 0, stream>>>(aux, NB);
    scan3_kernel<<<NB, 256, 0, stream>>>(offs, aux, count /*cursor*/, count, dinv, N, E);
    fill_kernel<<<(E + 255) / 256, 256, 0, stream>>>(src, dst, count /*cursor*/, adj, E);

    // ---- weight conversions ----
    convw_kernel<<<(128 * 128 + 255) / 256, 256, 0, stream>>>(W1, Wt1h, Wt1l, 128);
    convw_kernel<<<(64 * 128 + 255) / 256, 256, 0, stream>>>(W2, Wt2h, Wt2l, 64);

    const int GB = (N + 127) / 128;  // 782 gemm blocks

    // ---- layer 1: h1 = dinv*(x@W1), x split in-register ----
    gemm_mfma_kernel<128, true, true><<<GB, 256, 0, stream>>>(
        x, nullptr, nullptr, Wt1h, Wt1l, dinv, h1h, h1l, nullptr, N);
    gather128_kernel<<<(N + 3) / 4, 256, 0, stream>>>(h1h, h1l, offs, adj, dinv, b1, g1h, g1l, N);

    // ---- layer 2: h2 = dinv*(g1@W2) ----
    gemm_mfma_kernel<64, false, false><<<GB, 256, 0, stream>>>(
        nullptr, g1h, g1l, Wt2h, Wt2l, dinv, nullptr, nullptr, h2, N);
    gather64_lsm_kernel<<<(N + 3) / 4, 256, 0, stream>>>(h2, offs, adj, dinv, b2, out, N);
}

// Round 5
// 257.524 us; speedup vs baseline: 18.4830x; 1.5969x over previous
//
#include <hip/hip_runtime.h>
#include <hip/hip_bf16.h>
#include <stdint.h>

#define N_NODES 100000
#define NBUCK 250   // buckets for counting-sort CSR build
#define NPB   400   // nodes per bucket (250*400 = 100000 exactly)
#define PTILE 4096  // edges per partition tile
#define SEGCAP 8192 // max edges per bucket (mean 6400, sigma 80 -> 22 sigma)

typedef short short8 __attribute__((ext_vector_type(8)));
typedef float floatx4 __attribute__((ext_vector_type(4)));

__device__ __forceinline__ unsigned short f2bf(float x) {
    uint32_t u = __float_as_uint(x);
    return (unsigned short)((u + 0x7fff + ((u >> 16) & 1)) >> 16);  // RNE
}
__device__ __forceinline__ float bf2f(unsigned int h) {
    return __uint_as_float(h << 16);
}

// ---------------------------------------------------- CSR build (count-sort) -
__global__ __launch_bounds__(256) void zero_small_kernel(int* p, int n) {
    int i = threadIdx.x;
    if (i < n) p[i] = 0;
}

__global__ __launch_bounds__(256) void bucket_hist_kernel(const int* __restrict__ dst,
                                                          int* __restrict__ gCount, int E) {
    __shared__ int hist[NBUCK];
    int tid = threadIdx.x;
    for (int i = tid; i < NBUCK; i += 256) hist[i] = 0;
    __syncthreads();
    int stride = gridDim.x * 256;
    for (int e = blockIdx.x * 256 + tid; e < E; e += stride)
        atomicAdd(&hist[(unsigned)dst[e] / NPB], 1);
    __syncthreads();
    for (int i = tid; i < NBUCK; i += 256)
        if (hist[i]) atomicAdd(&gCount[i], hist[i]);
}

__global__ __launch_bounds__(256) void bucket_scan_kernel(const int* __restrict__ gCount,
                                                          int* __restrict__ gBase,
                                                          int* __restrict__ gCursor, int E) {
    __shared__ int sm[256];
    int tid = threadIdx.x;
    int v = (tid < NBUCK) ? gCount[tid] : 0;
    sm[tid] = v;
    __syncthreads();
#pragma unroll
    for (int off = 1; off < 256; off <<= 1) {
        int t = (tid >= off) ? sm[tid - off] : 0;
        __syncthreads();
        sm[tid] += t;
        __syncthreads();
    }
    if (tid < NBUCK) { int b = sm[tid] - v; gBase[tid] = b; gCursor[tid] = b; }
    if (tid == 0) gBase[NBUCK] = E;
}

// partition edges into bucket segments of pairs[] with LDS-staged coalesced flush
__global__ __launch_bounds__(256) void partition_kernel(const int* __restrict__ src,
                                                        const int* __restrict__ dst,
                                                        int* __restrict__ gCursor,
                                                        uint2* __restrict__ pairs, int E) {
    __shared__ int hist[NBUCK], toffs[NBUCK], gb[NBUCK], lpos[NBUCK];
    __shared__ int sm[256];
    __shared__ uint2 pairbuf[PTILE];
    __shared__ int gidx[PTILE];
    int tid = threadIdx.x;
    int ntiles = (E + PTILE - 1) / PTILE;
    for (int tile = blockIdx.x; tile < ntiles; tile += gridDim.x) {
        int base = tile * PTILE;
        int n = min(PTILE, E - base);
        for (int i = tid; i < NBUCK; i += 256) { hist[i] = 0; lpos[i] = 0; }
        __syncthreads();
        int es[16], ed[16], eb[16];
#pragma unroll
        for (int k = 0; k < 16; ++k) {
            int e = base + k * 256 + tid;
            if (e < base + n) {
                es[k] = src[e];
                ed[k] = dst[e];
                eb[k] = (int)((unsigned)ed[k] / NPB);
                atomicAdd(&hist[eb[k]], 1);
            } else eb[k] = -1;
        }
        __syncthreads();
        int v = (tid < NBUCK) ? hist[tid] : 0;
        sm[tid] = v;
        __syncthreads();
#pragma unroll
        for (int off = 1; off < 256; off <<= 1) {
            int t = (tid >= off) ? sm[tid - off] : 0;
            __syncthreads();
            sm[tid] += t;
            __syncthreads();
        }
        if (tid < NBUCK) {
            toffs[tid] = sm[tid] - v;
            if (v > 0) gb[tid] = atomicAdd(&gCursor[tid], v);
        }
        __syncthreads();
#pragma unroll
        for (int k = 0; k < 16; ++k) {
            int b = eb[k];
            if (b >= 0) {
                int p = toffs[b] + atomicAdd(&lpos[b], 1);
                pairbuf[p] = make_uint2((unsigned)es[k], (unsigned)ed[k]);
                gidx[p] = gb[b] + (p - toffs[b]);
            }
        }
        __syncthreads();
        for (int i = tid; i < n; i += 256)
            pairs[gidx[i]] = pairbuf[i];  // contiguous runs per bucket
        __syncthreads();
    }
}

// one block per bucket: per-node hist+scan -> offs/dinv, LDS scatter -> coalesced adj
__global__ __launch_bounds__(256) void bucket_csr_kernel(const uint2* __restrict__ pairs,
                                                         const int* __restrict__ gBase,
                                                         int* __restrict__ adj,
                                                         int* __restrict__ offs,
                                                         float* __restrict__ dinv,
                                                         int N, int E) {
    __shared__ int hist[NPB], excl[NPB], cursor[NPB];
    __shared__ int ladj[SEGCAP];
    __shared__ int sm[256];
    int b = blockIdx.x, tid = threadIdx.x;
    int nodeBase = b * NPB;
    int segBase = gBase[b], segEnd = gBase[b + 1];
    int cnt = segEnd - segBase;
    if (cnt > SEGCAP) cnt = SEGCAP;  // statistically unreachable guard
    for (int i = tid; i < NPB; i += 256) hist[i] = 0;
    __syncthreads();
    for (int i = tid; i < cnt; i += 256)
        atomicAdd(&hist[(int)pairs[segBase + i].y - nodeBase], 1);
    __syncthreads();
    int total = 0;
    for (int r = 0; r < 2; ++r) {
        int idx = r * 256 + tid;
        int v = (idx < NPB) ? hist[idx] : 0;
        sm[tid] = v;
        __syncthreads();
#pragma unroll
        for (int off = 1; off < 256; off <<= 1) {
            int t = (tid >= off) ? sm[tid - off] : 0;
            __syncthreads();
            sm[tid] += t;
            __syncthreads();
        }
        if (idx < NPB) {
            int e = total + sm[tid] - v;
            excl[idx] = e;
            cursor[idx] = e;
        }
        total += sm[255];
        __syncthreads();
    }
    for (int j = tid; j < NPB; j += 256) {
        offs[nodeBase + j] = segBase + excl[j];
        dinv[nodeBase + j] = rsqrtf((float)hist[j] + 1.0f);
    }
    if (b == NBUCK - 1 && tid == 0) offs[N] = E;
    __syncthreads();
    for (int i = tid; i < cnt; i += 256) {
        uint2 p = pairs[segBase + i];
        int pos = atomicAdd(&cursor[(int)p.y - nodeBase], 1);
        if (pos < SEGCAP) ladj[pos] = (int)p.x;
    }
    __syncthreads();
    for (int i = tid; i < cnt; i += 256) adj[segBase + i] = ladj[i];
}

// W [128 k][N n] fp32  ->  Wt hi/lo [N n][128 k] bf16 (transposed, linear)
__global__ __launch_bounds__(256) void convw_kernel(const float* __restrict__ W,
                                                    unsigned short* __restrict__ WtH,
                                                    unsigned short* __restrict__ WtL, int N) {
    int i = blockIdx.x * 256 + threadIdx.x;  // i = n*128 + k
    if (i >= N * 128) return;
    int n = i >> 7, k = i & 127;
    float v = W[k * N + n];
    unsigned short h = f2bf(v);
    WtH[i] = h;
    WtL[i] = f2bf(v - bf2f(h));
}

// ------------------------------------------------------------- MFMA GEMM ----
__device__ __forceinline__ void split8(const float* p, short8& h, short8& l) {
    float4 a = *(const float4*)p;
    float4 b = *(const float4*)(p + 4);
    float v[8] = {a.x, a.y, a.z, a.w, b.x, b.y, b.z, b.w};
#pragma unroll
    for (int i = 0; i < 8; ++i) {
        unsigned short hh = f2bf(v[i]);
        h[i] = (short)hh;
        l[i] = (short)f2bf(v[i] - bf2f(hh));
    }
}

// C[r][:] = dinv[r] * (A[r][:] @ W), 3-product bf16 split (Ah*Wh+Al*Wh+Ah*Wl).
template <int N, bool SPLIT_IN, bool SPLIT_OUT>
__global__ __launch_bounds__(256) void gemm_mfma_kernel(
    const float* __restrict__ Af,
    const unsigned short* __restrict__ Ah, const unsigned short* __restrict__ Al,
    const unsigned short* __restrict__ WtH, const unsigned short* __restrict__ WtL,
    const float* __restrict__ dinv,
    unsigned short* __restrict__ Ch, unsigned short* __restrict__ Cl,
    float* __restrict__ Cf, int nrows) {
    constexpr int NT = N / 16;
    __shared__ char Wl[2 * N * 256];  // hi then lo, 256 B per n-row, XOR-swizzled
    int tid = threadIdx.x;
    {
        const char* s0 = (const char*)WtH;
        const char* s1 = (const char*)WtL;
        const int chunks = N * 16;
        for (int i = tid; i < 2 * chunks; i += 256) {
            int buf = (i >= chunks) ? 1 : 0;
            int c = i - buf * chunks;
            int nn = c >> 4;
            float4 v = *(const float4*)((buf ? s1 : s0) + c * 16);
            int dstoff = (c * 16) ^ ((nn & 7) << 4);
            *(float4*)(Wl + buf * (N * 256) + dstoff) = v;
        }
    }
    __syncthreads();

    int wid = tid >> 6, lane = tid & 63;
    int rowbase = blockIdx.x * 128 + wid * 32;
    int lr = lane & 15, lg = lane >> 4;

    floatx4 acc[2][NT] = {};
    for (int ks = 0; ks < 4; ++ks) {
        short8 afh[2], afl[2];
#pragma unroll
        for (int rt = 0; rt < 2; ++rt) {
            int r = rowbase + rt * 16 + lr;
            if (r > nrows - 1) r = nrows - 1;
            size_t off = (size_t)r * 128 + ks * 32 + (lg << 3);
            if (SPLIT_IN) {
                split8(Af + off, afh[rt], afl[rt]);
            } else {
                afh[rt] = *(const short8*)(Ah + off);
                afl[rt] = *(const short8*)(Al + off);
            }
        }
#pragma unroll
        for (int t = 0; t < NT; ++t) {
            int nn = t * 16 + lr;
            int off = (nn * 256 + ks * 64 + (lg << 4)) ^ ((nn & 7) << 4);
            short8 bh = *(const short8*)(Wl + off);
            short8 bl = *(const short8*)(Wl + N * 256 + off);
#pragma unroll
            for (int rt = 0; rt < 2; ++rt) {
                acc[rt][t] = __builtin_amdgcn_mfma_f32_16x16x32_bf16(afh[rt], bh, acc[rt][t], 0, 0, 0);
                acc[rt][t] = __builtin_amdgcn_mfma_f32_16x16x32_bf16(afl[rt], bh, acc[rt][t], 0, 0, 0);
                acc[rt][t] = __builtin_amdgcn_mfma_f32_16x16x32_bf16(afh[rt], bl, acc[rt][t], 0, 0, 0);
            }
        }
    }
#pragma unroll
    for (int rt = 0; rt < 2; ++rt) {
#pragma unroll
        for (int j = 0; j < 4; ++j) {
            int row = rowbase + rt * 16 + lg * 4 + j;
            if (row >= nrows) continue;
            float dv = dinv[row];
#pragma unroll
            for (int t = 0; t < NT; ++t) {
                int col = t * 16 + lr;
                float v = acc[rt][t][j] * dv;
                if (SPLIT_OUT) {
                    unsigned short h = f2bf(v);
                    Ch[(size_t)row * N + col] = h;
                    Cl[(size_t)row * N + col] = f2bf(v - bf2f(h));
                } else {
                    Cf[(size_t)row * N + col] = v;
                }
            }
        }
    }
}

// ----------------------------------------------------------- gather aggs ----
// g[r] = relu(dr * (self_hi+lo + sum_adj hi) + b); h pre-scaled by dinv[src].
__global__ __launch_bounds__(256) void gather128_kernel(
    const unsigned short* __restrict__ hh, const unsigned short* __restrict__ hl,
    const int* __restrict__ offs, const int* __restrict__ adj,
    const float* __restrict__ dinv, const float* __restrict__ b,
    unsigned short* __restrict__ gh, unsigned short* __restrict__ gl, int n) {
    int wid = threadIdx.x >> 6, lane = threadIdx.x & 63;
    int r = blockIdx.x * 4 + wid;
    if (r >= n) return;
    float dr = dinv[r];
    uint32_t vh = *(const uint32_t*)(hh + (size_t)r * 128 + 2 * lane);
    uint32_t vl = *(const uint32_t*)(hl + (size_t)r * 128 + 2 * lane);
    float a0x = bf2f(vh & 0xffffu) + bf2f(vl & 0xffffu);
    float a0y = bf2f(vh >> 16) + bf2f(vl >> 16);
    float a1x = 0.f, a1y = 0.f, a2x = 0.f, a2y = 0.f, a3x = 0.f, a3y = 0.f;
    int e0 = offs[r], e1 = offs[r + 1];
    int j = e0;
    for (; j + 4 <= e1; j += 4) {
        int s0 = adj[j], s1 = adj[j + 1], s2 = adj[j + 2], s3 = adj[j + 3];
        uint32_t u0 = *(const uint32_t*)(hh + (size_t)s0 * 128 + 2 * lane);
        uint32_t u1 = *(const uint32_t*)(hh + (size_t)s1 * 128 + 2 * lane);
        uint32_t u2 = *(const uint32_t*)(hh + (size_t)s2 * 128 + 2 * lane);
        uint32_t u3 = *(const uint32_t*)(hh + (size_t)s3 * 128 + 2 * lane);
        a0x += bf2f(u0 & 0xffffu); a0y += bf2f(u0 >> 16);
        a1x += bf2f(u1 & 0xffffu); a1y += bf2f(u1 >> 16);
        a2x += bf2f(u2 & 0xffffu); a2y += bf2f(u2 >> 16);
        a3x += bf2f(u3 & 0xffffu); a3y += bf2f(u3 >> 16);
    }
    for (; j < e1; ++j) {
        int s = adj[j];
        uint32_t u = *(const uint32_t*)(hh + (size_t)s * 128 + 2 * lane);
        a0x += bf2f(u & 0xffffu); a0y += bf2f(u >> 16);
    }
    float accx = (a0x + a1x) + (a2x + a3x);
    float accy = (a0y + a1y) + (a2y + a3y);
    accx = fmaxf(fmaf(accx, dr, b[2 * lane]), 0.f);
    accy = fmaxf(fmaf(accy, dr, b[2 * lane + 1]), 0.f);
    unsigned short hx = f2bf(accx), hy = f2bf(accy);
    *(uint32_t*)(gh + (size_t)r * 128 + 2 * lane) = (uint32_t)hx | ((uint32_t)hy << 16);
    unsigned short lx = f2bf(accx - bf2f(hx)), ly = f2bf(accy - bf2f(hy));
    *(uint32_t*)(gl + (size_t)r * 128 + 2 * lane) = (uint32_t)lx | ((uint32_t)ly << 16);
}

// fused gather + bias + log_softmax over 64 cols (h2 bf16 hi/lo, pre-scaled)
__global__ __launch_bounds__(256) void gather64_lsm_kernel(
    const unsigned short* __restrict__ hh, const unsigned short* __restrict__ hl,
    const int* __restrict__ offs, const int* __restrict__ adj,
    const float* __restrict__ dinv, const float* __restrict__ b,
    float* __restrict__ out, int n) {
    int wid = threadIdx.x >> 6, lane = threadIdx.x & 63;
    int r = blockIdx.x * 4 + wid;
    if (r >= n) return;
    float dr = dinv[r];
    float a0 = bf2f(hh[(size_t)r * 64 + lane]) + bf2f(hl[(size_t)r * 64 + lane]);
    float a1 = 0.f, a2 = 0.f, a3 = 0.f;
    int e0 = offs[r], e1 = offs[r + 1];
    int j = e0;
    for (; j + 4 <= e1; j += 4) {
        int s0 = adj[j], s1 = adj[j + 1], s2 = adj[j + 2], s3 = adj[j + 3];
        a0 += bf2f(hh[(size_t)s0 * 64 + lane]);
        a1 += bf2f(hh[(size_t)s1 * 64 + lane]);
        a2 += bf2f(hh[(size_t)s2 * 64 + lane]);
        a3 += bf2f(hh[(size_t)s3 * 64 + lane]);
    }
    for (; j < e1; ++j) a0 += bf2f(hh[(size_t)adj[j] * 64 + lane]);
    float acc = (a0 + a1) + (a2 + a3);
    float v = fmaf(acc, dr, b[lane]);
    float m = v;
#pragma unroll
    for (int off = 32; off; off >>= 1) m = fmaxf(m, __shfl_xor(m, off));
    float ex = __expf(v - m);
    float sum = ex;
#pragma unroll
    for (int off = 32; off; off >>= 1) sum += __shfl_xor(sum, off);
    out[(size_t)r * 64 + lane] = v - m - __logf(sum);
}

// ---------------------------------------------------------------- launch ----
extern "C" void kernel_launch(void* const* d_in, const int* in_sizes, int n_in,
                              void* d_out, int out_size, void* d_ws, size_t ws_size,
                              hipStream_t stream) {
    const float* x  = (const float*)d_in[0];
    const int*   ei = (const int*)d_in[1];
    const float* W1 = (const float*)d_in[2];
    const float* b1 = (const float*)d_in[3];
    const float* W2 = (const float*)d_in[4];
    const float* b2 = (const float*)d_in[5];
    float* out = (float*)d_out;

    const int N = N_NODES;
    const int E = in_sizes[1] / 2;
    const int* src = ei;
    const int* dst = ei + E;

    char* ws = (char*)d_ws;
    float* dinv   = (float*)(ws + (0ll << 20));                  // 400 KB
    int* offs     = (int*)  (ws + (1ll << 20));                  // 400 KB + 4
    int* gCount   = (int*)  (ws + 1572864ll);                    // 1 KB
    int* gBase    = (int*)  (ws + 1576960ll);                    // 1 KB (+1)
    int* gCursor  = (int*)  (ws + 1581056ll);                    // 1 KB
    unsigned short* Wt1h = (unsigned short*)(ws + 1638400ll);    // 32 KB
    unsigned short* Wt1l = (unsigned short*)(ws + 1671168ll);    // 32 KB
    unsigned short* Wt2h = (unsigned short*)(ws + 1703936ll);    // 16 KB
    unsigned short* Wt2l = (unsigned short*)(ws + 1720320ll);    // 16 KB
    int* adj      = (int*)  (ws + (2ll << 20));                  // 6.4 MB
    unsigned short* g1h = (unsigned short*)(ws + (9ll  << 20));  // 25.6 MB
    unsigned short* g1l = (unsigned short*)(ws + (35ll << 20));  // 25.6 MB
    unsigned short* h1h = (unsigned short*)(ws + (61ll << 20));  // 25.6 MB
    unsigned short* h1l = (unsigned short*)(ws + (87ll << 20));  // 25.6 MB
    uint2* pairs  = (uint2*)h1h;            // 12.8 MB, dead before gemm1 writes h1
    unsigned short* h2h = h1h;              // 12.8 MB, after gather128 consumed h1
    unsigned short* h2l = h1h + (size_t)N * 64;  // 12.8 MB

    // ---- CSR build via two-level counting sort ----
    zero_small_kernel<<<1, 256, 0, stream>>>(gCount, NBUCK);
    bucket_hist_kernel<<<256, 256, 0, stream>>>(dst, gCount, E);
    bucket_scan_kernel<<<1, 256, 0, stream>>>(gCount, gBase, gCursor, E);
    int ntiles = (E + PTILE - 1) / PTILE;
    partition_kernel<<<ntiles, 256, 0, stream>>>(src, dst, gCursor, pairs, E);
    bucket_csr_kernel<<<NBUCK, 256, 0, stream>>>(pairs, gBase, adj, offs, dinv, N, E);

    // ---- weight conversions ----
    convw_kernel<<<(128 * 128 + 255) / 256, 256, 0, stream>>>(W1, Wt1h, Wt1l, 128);
    convw_kernel<<<(64 * 128 + 255) / 256, 256, 0, stream>>>(W2, Wt2h, Wt2l, 64);

    const int GB = (N + 127) / 128;  // 782 gemm blocks

    // ---- layer 1: h1 = dinv*(x@W1), x split in-register ----
    gemm_mfma_kernel<128, true, true><<<GB, 256, 0, stream>>>(
        x, nullptr, nullptr, Wt1h, Wt1l, dinv, h1h, h1l, nullptr, N);
    gather128_kernel<<<(N + 3) / 4, 256, 0, stream>>>(h1h, h1l, offs, adj, dinv, b1, g1h, g1l, N);

    // ---- layer 2: h2 = dinv*(g1@W2), bf16 hi/lo out ----
    gemm_mfma_kernel<64, false, true><<<GB, 256, 0, stream>>>(
        nullptr, g1h, g1l, Wt2h, Wt2l, dinv, h2h, h2l, nullptr, N);
    gather64_lsm_kernel<<<(N + 3) / 4, 256, 0, stream>>>(h2h, h2l, offs, adj, dinv, b2, out, N);
}